// Round 6
// baseline (334.760 us; speedup 1.0000x reference)
//
#include <hip/hip_runtime.h>
#include <hip/hip_bf16.h>

#define N_NODES 100000
#define N_HEDGES 20000
#define N_EDGES 800000
#define HSEG (2 * N_HEDGES)            // 40000 hedge segments (t,h)
#define NSEG (2 * N_NODES)             // 200000 node segments (t,n)
#define MSEG (HSEG + NSEG)             // 240000 segments
#define NSUB 8                          // per-XCD counter slices, sub = XCC_ID
#define TOT (MSEG * NSUB)               // 1,920,000 counters, SEG-MAJOR layout:
                                        // cnt[seg*8+sub] -> each segment's 8
                                        // sub-runs are CONTIGUOUS in sortedAll
#define SCAN_BLOCKS ((TOT + 2047) / 2048)  // 938

#define HIST_BLOCKS ((N_EDGES + 255) / 256)        // 3125
#define CAST_BLOCKS (N_NODES * 64 / 8 / 256)       // 3125
#define PACK_BLOCKS 16

#define MIX_PK  (4 * 4 * 64 * 8)        // 8192 packed bf16 fused-mix weights
#define GRU_PK  (2 * 2 * 12 * 64 * 8)   // 24576 for k_mixgru

typedef __hip_bfloat16 bf16;
typedef __attribute__((ext_vector_type(8))) short bf16x8;
typedef __attribute__((ext_vector_type(4))) float f32x4;

__device__ __forceinline__ bf16 f2b(float v) { return __float2bfloat16(v); }
__device__ __forceinline__ short f2s(float v) {
    bf16 b = __float2bfloat16(v);
    return *reinterpret_cast<short*>(&b);
}
__device__ __forceinline__ uint pk2(float a, float b) {
    return (uint)(unsigned short)f2s(a) | ((uint)(unsigned short)f2s(b) << 16);
}
__device__ __forceinline__ bf16x8 pack8(float4 a, float4 b) {
    bf16x8 r = {f2s(a.x), f2s(a.y), f2s(a.z), f2s(a.w),
                f2s(b.x), f2s(b.y), f2s(b.z), f2s(b.w)};
    return r;
}
__device__ __forceinline__ float fast_sigmoid(float x) {
    return __builtin_amdgcn_rcpf(1.f + __expf(-x));
}
__device__ __forceinline__ float fast_tanh(float x) {
    return 1.f - 2.f * __builtin_amdgcn_rcpf(1.f + __expf(2.f * x));
}

// ---------------------------------------------------------------------------
// FRONT kernel: three independent roles by blockIdx range (one launch):
//  [0, HIST)         histogram + rank recording, XCD-local L2 atomics
//  [HIST, +CAST)     x -> bf16 cast
//  [+CAST, +PACK)    weight packing + conv/mix fusion (Wf = Wc @ Wm_t)
// Histogram trick: counters partitioned by PHYSICAL XCD (s_getreg XCC_ID);
// every update to cnt[seg*8+sub] comes from XCD `sub` only, so a
// WORKGROUP-scope atomic (no sc1 -> executes in the XCD's own L2) is
// globally correct — avoiding the 32B/atomic memory-side fabric traffic
// that capped k_hist at ~66us for 3 rounds. sub is packed into r1[31:16].
// ---------------------------------------------------------------------------
__global__ __launch_bounds__(256) void k_front(
    const int* __restrict__ node_idx, const int* __restrict__ hedge_idx,
    const int* __restrict__ attr, int* __restrict__ cnt,
    int* __restrict__ r1, int* __restrict__ r2,
    const float* __restrict__ x, bf16* __restrict__ xb,
    const float* __restrict__ Wc, const float* __restrict__ Wm,
    const float* __restrict__ bc, const float* __restrict__ bm,
    const float* __restrict__ Wih, const float* __restrict__ Whh,
    bf16* __restrict__ gru_pk, bf16* __restrict__ mixf_pk,
    float* __restrict__ bfused) {
    int b = blockIdx.x;
    if (b < HIST_BLOCKS) {
        uint xcc;
        asm volatile("s_getreg_b32 %0, hwreg(HW_REG_XCC_ID, 0, 32)" : "=s"(xcc));
        int sub = (int)(xcc & 7u);
        int e = b * 256 + threadIdx.x;
        if (e < N_EDGES) {
            int t = attr[e];
            int s1 = t * N_HEDGES + hedge_idx[e];
            int s2 = HSEG + t * N_NODES + node_idx[e];
            int a1 = __hip_atomic_fetch_add(&cnt[s1 * NSUB + sub], 1,
                         __ATOMIC_RELAXED, __HIP_MEMORY_SCOPE_WORKGROUP);
            int a2 = __hip_atomic_fetch_add(&cnt[s2 * NSUB + sub], 1,
                         __ATOMIC_RELAXED, __HIP_MEMORY_SCOPE_WORKGROUP);
            r1[e] = a1 | (sub << 16);   // ranks < 2^16 (max seg degree ~100)
            r2[e] = a2;
        }
    } else if (b < HIST_BLOCKS + CAST_BLOCKS) {
        size_t i = ((size_t)(b - HIST_BLOCKS) * 256 + threadIdx.x) * 8;
        const float* xp = x + i;
        float4 a = *(const float4*)xp;
        float4 bb = *(const float4*)(xp + 4);
        *(bf16x8*)(xb + i) = pack8(a, bb);
    } else {
        int idx = (b - HIST_BLOCKS - CAST_BLOCKS) * 256 + threadIdx.x;
        int stride = PACK_BLOCKS * 256;
        for (int i = idx; i < GRU_PK; i += stride) {
            int j = i & 7;
            int r = i >> 3;
            int ln = r & 63;
            int r2i = r >> 6;
            int ct = r2i % 12;
            int r3 = r2i / 12;
            int kt = r3 & 1;
            int mat = r3 >> 1;
            int k = kt * 32 + ((ln >> 4) << 3) + j;
            int n = ct * 16 + (ln & 15);
            float v = mat == 0 ? Wih[k * 192 + n] : Whh[k * 192 + n];
            gru_pk[i] = f2b(v);
        }
        for (int i = idx; i < MIX_PK; i += stride) {
            int j = i & 7, ln = (i >> 3) & 63, r2i = i >> 9;
            int ct = r2i & 3, kt = r2i >> 2;
            int k = kt * 32 + ((ln >> 4) << 3) + j;   // 0..127 (concat dim)
            int n = ct * 16 + (ln & 15);
            int t = k >> 6, kk = k & 63;
            float s = 0.f;
            for (int q = 0; q < 64; ++q)
                s += Wc[((size_t)t * 64 + kk) * 64 + q] * Wm[(size_t)(t * 64 + q) * 64 + n];
            mixf_pk[i] = f2b(s);
        }
        for (int i = idx; i < 64; i += stride) {
            float s = bm[i];
            for (int q = 0; q < 64; ++q)
                s += bc[q] * Wm[(size_t)q * 64 + i] + bc[64 + q] * Wm[(size_t)(64 + q) * 64 + i];
            bfused[i] = s;
        }
    }
}

// ---------------------------------------------------------------------------
// Scan 1/3: 2048 elems/block (256 thr x 8), partial exclusive scan + bsum.
// ---------------------------------------------------------------------------
__global__ __launch_bounds__(256) void k_scan1(const int* __restrict__ cnt,
                                               int* __restrict__ off,
                                               int* __restrict__ bsum) {
    __shared__ int s[256];
    int base = blockIdx.x * 2048 + threadIdx.x * 8;
    int v[8];
    int tsum = 0;
#pragma unroll
    for (int j = 0; j < 8; ++j) {
        int g = base + j;
        v[j] = (g < TOT) ? cnt[g] : 0;
        tsum += v[j];
    }
    s[threadIdx.x] = tsum;
    __syncthreads();
    for (int o = 1; o < 256; o <<= 1) {
        int t = (threadIdx.x >= o) ? s[threadIdx.x - o] : 0;
        __syncthreads();
        s[threadIdx.x] += t;
        __syncthreads();
    }
    int run = s[threadIdx.x] - tsum;
#pragma unroll
    for (int j = 0; j < 8; ++j) {
        int g = base + j;
        if (g < TOT) off[g] = run;
        run += v[j];
    }
    if (threadIdx.x == 255) bsum[blockIdx.x] = s[255];
}

// ---------------------------------------------------------------------------
// Scan 2/3: exclusive scan of SCAN_BLOCKS (<=1024) block sums, one block.
// ---------------------------------------------------------------------------
__global__ __launch_bounds__(1024) void k_scan2(int* __restrict__ bsum) {
    __shared__ int s[1024];
    int tid = threadIdx.x;
    int v = (tid < SCAN_BLOCKS) ? bsum[tid] : 0;
    s[tid] = v;
    __syncthreads();
    for (int o = 1; o < 1024; o <<= 1) {
        int t = (tid >= o) ? s[tid - o] : 0;
        __syncthreads();
        s[tid] += t;
        __syncthreads();
    }
    if (tid < SCAN_BLOCKS) bsum[tid] = s[tid] - v;
}

// ---------------------------------------------------------------------------
// Scan 3/3: finalize off in place (+ sentinel off[TOT] = 2*N_EDGES).
// ---------------------------------------------------------------------------
__global__ __launch_bounds__(256) void k_scan3(int* __restrict__ off,
                                               const int* __restrict__ bsum) {
    int base = blockIdx.x * 2048 + threadIdx.x * 8;
    int add = bsum[blockIdx.x];
#pragma unroll
    for (int j = 0; j < 8; ++j) {
        int g = base + j;
        if (g < TOT) off[g] += add;
    }
    if (blockIdx.x == 0 && threadIdx.x == 0) off[TOT] = 2 * N_EDGES;
}

// ---------------------------------------------------------------------------
// Scatter, ATOMIC-FREE: position = off[seg*8 + sub] + rank (sub from r1 hi).
// ---------------------------------------------------------------------------
__global__ __launch_bounds__(256) void k_scatter(const int* __restrict__ node_idx,
                                                 const int* __restrict__ hedge_idx,
                                                 const int* __restrict__ attr,
                                                 const int* __restrict__ off,
                                                 const int* __restrict__ r1,
                                                 const int* __restrict__ r2,
                                                 int* __restrict__ sortedAll) {
    int e = blockIdx.x * 256 + threadIdx.x;
    if (e < N_EDGES) {
        int t = attr[e], n = node_idx[e], h = hedge_idx[e];
        int rv1 = r1[e];
        int sub = rv1 >> 16;
        int p1 = off[(t * N_HEDGES + h) * NSUB + sub] + (rv1 & 0xFFFF);
        sortedAll[p1] = n;
        int p2 = off[(HSEG + t * N_NODES + n) * NSUB + sub] + r2[e];
        sortedAll[p2] = t * N_HEDGES + h;
    }
}

// ---------------------------------------------------------------------------
// Quarter-per-segment gather. Seg-major counter layout keeps each segment's
// entries CONTIGUOUS (one run spanning its 8 sub-slices): beg = off[seg*8],
// end = off[(seg+1)*8]. 8-lane half-groups process even/odd elements with
// uint4 reads; shfl_xor(8) combine; lanes 0..7 of each quarter store 16B.
// ---------------------------------------------------------------------------
__device__ __forceinline__ void seg_gather(const int* __restrict__ off,
                                           const int* __restrict__ sortedAll,
                                           const bf16* __restrict__ rows,
                                           int seg0, int lane,
                                           float acc[8], int* total) {
    int q = lane >> 4, l16 = lane & 15;
    int ov = 0;
    if (lane < 5) ov = off[(size_t)(seg0 + lane) * NSUB];  // 4 segs: begs+ends
    int myb = __shfl(ov, q);
    int mye = __shfl(ov, q + 1);
#pragma unroll
    for (int j = 0; j < 8; ++j) acc[j] = 0.f;
    for (int i = myb + (l16 >> 3); i < mye; i += 2) {
        int idx = sortedAll[i];            // broadcast within 8-lane group
        uint4 v = *(const uint4*)(rows + (size_t)idx * 64 + (l16 & 7) * 8);
        acc[0] += __uint_as_float(v.x << 16);
        acc[1] += __uint_as_float(v.x & 0xffff0000u);
        acc[2] += __uint_as_float(v.y << 16);
        acc[3] += __uint_as_float(v.y & 0xffff0000u);
        acc[4] += __uint_as_float(v.z << 16);
        acc[5] += __uint_as_float(v.z & 0xffff0000u);
        acc[6] += __uint_as_float(v.w << 16);
        acc[7] += __uint_as_float(v.w & 0xffff0000u);
    }
#pragma unroll
    for (int j = 0; j < 8; ++j) acc[j] += __shfl_xor(acc[j], 8);
    *total = mye - myb;
}

// CSR node->hedge: ef_raw[t][h] = (1/B) * sum xb rows (RAW x, no weights).
__global__ __launch_bounds__(256) void k_ef2(const int* __restrict__ off,
                                             const int* __restrict__ sortedAll,
                                             const bf16* __restrict__ xb,
                                             bf16* __restrict__ ef16) {
    int wid = threadIdx.x >> 6, lane = threadIdx.x & 63;
    int seg0 = (blockIdx.x * 4 + wid) * 4;
    if (seg0 >= HSEG) return;
    float acc[8];
    int tot;
    seg_gather(off, sortedAll, xb, seg0, lane, acc, &tot);
    float scale = tot > 0 ? 1.0f / (float)tot : 0.f;
    int q = lane >> 4, l16 = lane & 15;
    if (l16 < 8) {
        int s = seg0 + q;
        uint4 w;
        w.x = pk2(acc[0] * scale, acc[1] * scale);
        w.y = pk2(acc[2] * scale, acc[3] * scale);
        w.z = pk2(acc[4] * scale, acc[5] * scale);
        w.w = pk2(acc[6] * scale, acc[7] * scale);
        *(uint4*)(ef16 + (size_t)s * 64 + l16 * 8) = w;
    }
}

// CSR hedge->node: agg[t][n] = (1/D) * sum ef_raw rows. Bias folded into
// bfused (k_mixgru), so no add here.
__global__ __launch_bounds__(256) void k_no2(const int* __restrict__ off,
                                             const int* __restrict__ sortedAll,
                                             const bf16* __restrict__ ef16,
                                             bf16* __restrict__ agg16) {
    int wid = threadIdx.x >> 6, lane = threadIdx.x & 63;
    int j0 = (blockIdx.x * 4 + wid) * 4;
    if (j0 >= NSEG) return;
    float acc[8];
    int tot;
    seg_gather(off, sortedAll, ef16, HSEG + j0, lane, acc, &tot);
    float scale = tot > 0 ? 1.0f / (float)tot : 0.f;
    int q = lane >> 4, l16 = lane & 15;
    if (l16 < 8) {
        int j = j0 + q;
        uint4 w;
        w.x = pk2(acc[0] * scale, acc[1] * scale);
        w.y = pk2(acc[2] * scale, acc[3] * scale);
        w.z = pk2(acc[4] * scale, acc[5] * scale);
        w.w = pk2(acc[6] * scale, acc[7] * scale);
        *(uint4*)(agg16 + (size_t)j * 64 + l16 * 8) = w;
    }
}

// ---------------------------------------------------------------------------
// FUSED mix+GRU (unchanged — passed rounds 4/5). Per 16-row tile:
// mix MFMA -> per-wave LDS bounce (chunk-XOR swizzle, same-wave DS order) ->
// GRU MFMA chains (r/z gates fused gi+gh+bias), fast sigmoid/tanh.
// ---------------------------------------------------------------------------
#define GRU_TILES (N_NODES / 16)
__global__ __launch_bounds__(256) void k_mixgru(const bf16* __restrict__ gru_pk,
                                                const bf16* __restrict__ mixf_pk,
                                                const float* __restrict__ bfused,
                                                const bf16* __restrict__ agg16,
                                                const float* __restrict__ h_prev,
                                                const float* __restrict__ bih_g,
                                                const float* __restrict__ bhh_g,
                                                const float* __restrict__ Wro_g,
                                                const float* __restrict__ bro_g,
                                                float* __restrict__ out_h,
                                                float* __restrict__ out_o) {
    __shared__ __align__(16) bf16 Wpk[GRU_PK];      // 48 KB
    __shared__ __align__(16) bf16 Wmx[MIX_PK];      // 16 KB
    __shared__ __align__(16) bf16 bounce[4 * 1024]; // 4 waves x 16x64 bf16 = 8 KB
    {
        const bf16x8* src = (const bf16x8*)gru_pk;
        bf16x8* dst = (bf16x8*)Wpk;
        for (int i = threadIdx.x; i < GRU_PK / 8; i += 256) dst[i] = src[i];
        const bf16x8* src2 = (const bf16x8*)mixf_pk;
        bf16x8* dst2 = (bf16x8*)Wmx;
        for (int i = threadIdx.x; i < MIX_PK / 8; i += 256) dst2[i] = src2[i];
    }
    __syncthreads();

    int wid = threadIdx.x >> 6, lane = threadIdx.x & 63;
    int quad = lane >> 4, l16 = lane & 15;
    bf16* bnc = &bounce[wid * 1024];

    float bmv[4];
#pragma unroll
    for (int ct = 0; ct < 4; ++ct) bmv[ct] = bfused[ct * 16 + l16];

    float br_c[4], bz_c[4], bin_c[4], bhn_c[4], wv[4][3];
#pragma unroll
    for (int cc = 0; cc < 4; ++cc) {
        int col = cc * 16 + l16;
        br_c[cc] = bih_g[col] + bhh_g[col];
        bz_c[cc] = bih_g[64 + col] + bhh_g[64 + col];
        bin_c[cc] = bih_g[128 + col];
        bhn_c[cc] = bhh_g[128 + col];
        wv[cc][0] = Wro_g[col * 64 + 0];
        wv[cc][1] = Wro_g[col * 64 + 1];
        wv[cc][2] = Wro_g[col * 64 + 2];
    }
    float bro0 = bro_g[0], bro1 = bro_g[1], bro2 = bro_g[2];

    int wave = blockIdx.x * 4 + wid;
    int n_waves = gridDim.x * 4;

    for (int tile = wave; tile < GRU_TILES; tile += n_waves) {
        int row0 = tile * 16;
        int arow = row0 + l16;

        // ---- mix ----
        bf16x8 af[4];
#pragma unroll
        for (int kt = 0; kt < 4; ++kt) {
            const bf16* src = (kt < 2)
                ? agg16 + (size_t)arow * 64 + kt * 32 + quad * 8
                : agg16 + ((size_t)N_NODES + arow) * 64 + (kt - 2) * 32 + quad * 8;
            af[kt] = *(const bf16x8*)src;
        }
#define LDBM(kt, ct) (*(const bf16x8*)&Wmx[(((kt)*4 + (ct)) * 64 + lane) * 8])
#pragma unroll
        for (int ct = 0; ct < 4; ++ct) {
            f32x4 acc = {bmv[ct], bmv[ct], bmv[ct], bmv[ct]};
#pragma unroll
            for (int kt = 0; kt < 4; ++kt)
                acc = __builtin_amdgcn_mfma_f32_16x16x32_bf16(af[kt], LDBM(kt, ct), acc, 0, 0, 0);
            // D-layout store into per-wave bounce, chunk-XOR swizzled.
#pragma unroll
            for (int rg = 0; rg < 4; ++rg) {
                int r = quad * 4 + rg;                       // local row
                int chunk = ct * 2 + (l16 >> 3);             // 8-col chunk
                int cs = chunk ^ (r & 7);                    // swizzled
                bnc[r * 64 + cs * 8 + (l16 & 7)] = f2b(fmaxf(acc[rg], 0.f));
            }
        }
#undef LDBM
        asm volatile("s_waitcnt lgkmcnt(0)" ::: "memory");
        __builtin_amdgcn_sched_barrier(0);

        // ---- re-read as A-fragments (row l16, chunks quad / quad+4) ----
        bf16x8 ha0 = *(const bf16x8*)&bnc[l16 * 64 + (quad ^ (l16 & 7)) * 8];
        bf16x8 ha1 = *(const bf16x8*)&bnc[l16 * 64 + ((quad + 4) ^ (l16 & 7)) * 8];

        const float* pp = h_prev + (size_t)arow * 64 + quad * 8;
        bf16x8 pa0 = pack8(*(const float4*)pp, *(const float4*)(pp + 4));
        bf16x8 pa1 = pack8(*(const float4*)(pp + 32), *(const float4*)(pp + 36));

        float p[4][3];
#pragma unroll
        for (int rg = 0; rg < 4; ++rg) p[rg][0] = p[rg][1] = p[rg][2] = 0.f;

#pragma unroll
        for (int cc = 0; cc < 4; ++cc) {
#define LDB(mat, kt, ct) (*(const bf16x8*)&Wpk[((((mat)*2 + (kt)) * 12 + (ct)) * 64 + lane) * 8])
            f32x4 rs = {br_c[cc], br_c[cc], br_c[cc], br_c[cc]};
            f32x4 zs = {bz_c[cc], bz_c[cc], bz_c[cc], bz_c[cc]};
            f32x4 gin = {bin_c[cc], bin_c[cc], bin_c[cc], bin_c[cc]};
            f32x4 ghn = {bhn_c[cc], bhn_c[cc], bhn_c[cc], bhn_c[cc]};
            rs = __builtin_amdgcn_mfma_f32_16x16x32_bf16(ha0, LDB(0, 0, cc), rs, 0, 0, 0);
            rs = __builtin_amdgcn_mfma_f32_16x16x32_bf16(ha1, LDB(0, 1, cc), rs, 0, 0, 0);
            rs = __builtin_amdgcn_mfma_f32_16x16x32_bf16(pa0, LDB(1, 0, cc), rs, 0, 0, 0);
            rs = __builtin_amdgcn_mfma_f32_16x16x32_bf16(pa1, LDB(1, 1, cc), rs, 0, 0, 0);
            zs = __builtin_amdgcn_mfma_f32_16x16x32_bf16(ha0, LDB(0, 0, cc + 4), zs, 0, 0, 0);
            zs = __builtin_amdgcn_mfma_f32_16x16x32_bf16(ha1, LDB(0, 1, cc + 4), zs, 0, 0, 0);
            zs = __builtin_amdgcn_mfma_f32_16x16x32_bf16(pa0, LDB(1, 0, cc + 4), zs, 0, 0, 0);
            zs = __builtin_amdgcn_mfma_f32_16x16x32_bf16(pa1, LDB(1, 1, cc + 4), zs, 0, 0, 0);
            gin = __builtin_amdgcn_mfma_f32_16x16x32_bf16(ha0, LDB(0, 0, cc + 8), gin, 0, 0, 0);
            gin = __builtin_amdgcn_mfma_f32_16x16x32_bf16(ha1, LDB(0, 1, cc + 8), gin, 0, 0, 0);
            ghn = __builtin_amdgcn_mfma_f32_16x16x32_bf16(pa0, LDB(1, 0, cc + 8), ghn, 0, 0, 0);
            ghn = __builtin_amdgcn_mfma_f32_16x16x32_bf16(pa1, LDB(1, 1, cc + 8), ghn, 0, 0, 0);
#undef LDB
#pragma unroll
            for (int rg = 0; rg < 4; ++rg) {
                int row = row0 + quad * 4 + rg;
                float pv = h_prev[(size_t)row * 64 + cc * 16 + l16];
                float rr = fast_sigmoid(rs[rg]);
                float zz = fast_sigmoid(zs[rg]);
                float nn = fast_tanh(gin[rg] + rr * ghn[rg]);
                float hn = (1.f - zz) * nn + zz * pv;
                out_h[(size_t)row * 64 + cc * 16 + l16] = hn;
                p[rg][0] += hn * wv[cc][0];
                p[rg][1] += hn * wv[cc][1];
                p[rg][2] += hn * wv[cc][2];
            }
        }
#pragma unroll
        for (int rg = 0; rg < 4; ++rg) {
#pragma unroll
            for (int m = 1; m < 16; m <<= 1) {
                p[rg][0] += __shfl_xor(p[rg][0], m);
                p[rg][1] += __shfl_xor(p[rg][1], m);
                p[rg][2] += __shfl_xor(p[rg][2], m);
            }
        }
        if (l16 == 0) {
#pragma unroll
            for (int rg = 0; rg < 4; ++rg) {
                int row = row0 + quad * 4 + rg;
                out_o[(size_t)row * 3 + 0] = p[rg][0] + bro0;
                out_o[(size_t)row * 3 + 1] = p[rg][1] + bro1;
                out_o[(size_t)row * 3 + 2] = p[rg][2] + bro2;
            }
        }
    }
}

extern "C" void kernel_launch(void* const* d_in, const int* in_sizes, int n_in,
                              void* d_out, int out_size, void* d_ws, size_t ws_size,
                              hipStream_t stream) {
    const float* x        = (const float*)d_in[0];
    const float* h_prev   = (const float*)d_in[1];
    const int* node_idx   = (const int*)d_in[2];
    const int* hedge_idx  = (const int*)d_in[3];
    const int* edge_attr  = (const int*)d_in[4];
    const float* W_conv   = (const float*)d_in[5];
    const float* b_conv   = (const float*)d_in[6];
    const float* W_mix    = (const float*)d_in[7];
    const float* b_mix    = (const float*)d_in[8];
    const float* W_ih     = (const float*)d_in[9];
    const float* W_hh     = (const float*)d_in[10];
    const float* b_ih     = (const float*)d_in[11];
    const float* b_hh     = (const float*)d_in[12];
    const float* W_ro     = (const float*)d_in[13];
    const float* b_ro     = (const float*)d_in[14];

    char* p = (char*)d_ws;
    auto alloc = [&](size_t bytes) {
        char* r = p;
        p += (bytes + 63) & ~(size_t)63;
        return r;
    };
    // Region A: cnt (dead after k_scan1) + bsum (dead after k_scan3),
    // overlaid by agg16 (first written in k_no2). 25.6MB >= 7.7MB+4KB.
    char* regA     = alloc((size_t)2 * N_NODES * 64 * 2);   // 25.6 MB
    int* cnt       = (int*)regA;
    int* bsum      = cnt + TOT;
    bf16* agg16    = (bf16*)regA;
    int* off       = (int*)alloc((size_t)(TOT + 1) * 4);    // live CSR ptrs
    int* sortedAll = (int*)alloc((size_t)2 * N_EDGES * 4);
    int* r1        = (int*)alloc((size_t)N_EDGES * 4);
    int* r2        = (int*)alloc((size_t)N_EDGES * 4);
    bf16* xb       = (bf16*)alloc((size_t)N_NODES * 64 * 2);
    bf16* ef16     = (bf16*)alloc((size_t)HSEG * 64 * 2);
    bf16* gru_pk   = (bf16*)alloc((size_t)GRU_PK * 2);
    bf16* mixf_pk  = (bf16*)alloc((size_t)MIX_PK * 2);
    float* bfused  = (float*)alloc(64 * 4);

    hipMemsetAsync(cnt, 0, (size_t)TOT * 4, stream);

    float* out_h = (float*)d_out;
    float* out_o = out_h + (size_t)N_NODES * 64;

    k_front<<<HIST_BLOCKS + CAST_BLOCKS + PACK_BLOCKS, 256, 0, stream>>>(
        node_idx, hedge_idx, edge_attr, cnt, r1, r2, x, xb,
        W_conv, W_mix, b_conv, b_mix, W_ih, W_hh, gru_pk, mixf_pk, bfused);
    k_scan1<<<SCAN_BLOCKS, 256, 0, stream>>>(cnt, off, bsum);
    k_scan2<<<1, 1024, 0, stream>>>(bsum);
    k_scan3<<<SCAN_BLOCKS, 256, 0, stream>>>(off, bsum);
    k_scatter<<<(N_EDGES + 255) / 256, 256, 0, stream>>>(node_idx, hedge_idx, edge_attr,
                                                         off, r1, r2, sortedAll);
    k_ef2<<<HSEG / 16, 256, 0, stream>>>(off, sortedAll, xb, ef16);
    k_no2<<<NSEG / 16, 256, 0, stream>>>(off, sortedAll, ef16, agg16);
    k_mixgru<<<512, 256, 0, stream>>>(gru_pk, mixf_pk, bfused, agg16, h_prev,
                                      b_ih, b_hh, W_ro, b_ro, out_h, out_o);
}

// Round 7
// 258.615 us; speedup vs baseline: 1.2944x; 1.2944x over previous
//
#include <hip/hip_runtime.h>
#include <hip/hip_bf16.h>

#define N_NODES 100000
#define N_HEDGES 20000
#define N_EDGES 800000
#define HSEG (2 * N_HEDGES)            // 40000 hedge segments (t,h)
#define NSEG (2 * N_NODES)             // 200000 node segments (t,n)
#define MSEG (HSEG + NSEG)             // 240000 segments

// Two-level LDS bucket sort geometry:
#define EPB 4096                        // edges per pass-A/C block
#define NBLK_A ((N_EDGES + EPB - 1) / EPB)  // 196
#define NHB 313                         // hedge buckets: 128 segs each
#define NBUCK 704                       // + 391 node buckets: 512 segs each
#define TOTB (NBUCK * NBLK_A)           // 137,984 (bucket-major counts)
#define SCANB ((TOTB + 2047) / 2048)    // 68
#define RKCAP 8192                      // max entries/bucket (mean ~2.3K)

#define CAST_BLOCKS (N_NODES * 64 / 8 / 256)   // 3125
#define PACK_BLOCKS 16

#define MIX_PK  (4 * 4 * 64 * 8)        // 8192 packed bf16 fused-mix weights
#define GRU_PK  (2 * 2 * 12 * 64 * 8)   // 24576 for k_mixgru

typedef __hip_bfloat16 bf16;
typedef __attribute__((ext_vector_type(8))) short bf16x8;
typedef __attribute__((ext_vector_type(4))) float f32x4;

__device__ __forceinline__ bf16 f2b(float v) { return __float2bfloat16(v); }
__device__ __forceinline__ short f2s(float v) {
    bf16 b = __float2bfloat16(v);
    return *reinterpret_cast<short*>(&b);
}
__device__ __forceinline__ uint pk2(float a, float b) {
    return (uint)(unsigned short)f2s(a) | ((uint)(unsigned short)f2s(b) << 16);
}
__device__ __forceinline__ bf16x8 pack8(float4 a, float4 b) {
    bf16x8 r = {f2s(a.x), f2s(a.y), f2s(a.z), f2s(a.w),
                f2s(b.x), f2s(b.y), f2s(b.z), f2s(b.w)};
    return r;
}
__device__ __forceinline__ float fast_sigmoid(float x) {
    return __builtin_amdgcn_rcpf(1.f + __expf(-x));
}
__device__ __forceinline__ float fast_tanh(float x) {
    return 1.f - 2.f * __builtin_amdgcn_rcpf(1.f + __expf(2.f * x));
}
__device__ __forceinline__ int bucket_of(int seg) {
    return (seg < HSEG) ? (seg >> 7) : (NHB + ((seg - HSEG) >> 9));
}

// ---------------------------------------------------------------------------
// FRONT kernel, three roles by blockIdx:
//  [0, NBLK_A)     bucket-sort pass A: LDS histogram of 704 buckets over
//                  4096 edges; LDS atomic return = rank (packed to rk12);
//                  per-block bucket counts -> bcnt (bucket-major). ZERO
//                  global atomics (rounds 2-6 proved ~1.6M global atomic
//                  RMWs cost a fixed ~65us regardless of scope/ILP/layout).
//  [.., +CAST)     x -> bf16 cast
//  [.., +PACK)     weight packing + conv/mix fusion (Wf = Wc @ Wm_t)
// ---------------------------------------------------------------------------
__global__ __launch_bounds__(256) void k_front(
    const int* __restrict__ node_idx, const int* __restrict__ hedge_idx,
    const int* __restrict__ attr, uint* __restrict__ rk12,
    int* __restrict__ bcnt,
    const float* __restrict__ x, bf16* __restrict__ xb,
    const float* __restrict__ Wc, const float* __restrict__ Wm,
    const float* __restrict__ bc_g, const float* __restrict__ bm,
    const float* __restrict__ Wih, const float* __restrict__ Whh,
    bf16* __restrict__ gru_pk, bf16* __restrict__ mixf_pk,
    float* __restrict__ bfused) {
    __shared__ int bc[NBUCK];
    int b = blockIdx.x;
    int tid = threadIdx.x;
    if (b < NBLK_A) {
        for (int i = tid; i < NBUCK; i += 256) bc[i] = 0;
        __syncthreads();
        int e0 = b * EPB;
        for (int it = 0; it < EPB / 256; ++it) {
            int e = e0 + it * 256 + tid;
            if (e < N_EDGES) {
                int t = attr[e];
                int s1 = t * N_HEDGES + hedge_idx[e];
                int s2 = HSEG + t * N_NODES + node_idx[e];
                int b1 = s1 >> 7;
                int b2 = NHB + ((s2 - HSEG) >> 9);
                int r1 = atomicAdd(&bc[b1], 1);
                int r2 = atomicAdd(&bc[b2], 1);
                rk12[e] = (uint)(r1 & 0xFFFF) | ((uint)r2 << 16);
            }
        }
        __syncthreads();
        for (int i = tid; i < NBUCK; i += 256) bcnt[i * NBLK_A + b] = bc[i];
    } else if (b < NBLK_A + CAST_BLOCKS) {
        size_t i = ((size_t)(b - NBLK_A) * 256 + tid) * 8;
        const float* xp = x + i;
        float4 a = *(const float4*)xp;
        float4 bb = *(const float4*)(xp + 4);
        *(bf16x8*)(xb + i) = pack8(a, bb);
    } else {
        int idx = (b - NBLK_A - CAST_BLOCKS) * 256 + tid;
        int stride = PACK_BLOCKS * 256;
        for (int i = idx; i < GRU_PK; i += stride) {
            int j = i & 7;
            int r = i >> 3;
            int ln = r & 63;
            int r2i = r >> 6;
            int ct = r2i % 12;
            int r3 = r2i / 12;
            int kt = r3 & 1;
            int mat = r3 >> 1;
            int k = kt * 32 + ((ln >> 4) << 3) + j;
            int n = ct * 16 + (ln & 15);
            float v = mat == 0 ? Wih[k * 192 + n] : Whh[k * 192 + n];
            gru_pk[i] = f2b(v);
        }
        for (int i = idx; i < MIX_PK; i += stride) {
            int j = i & 7, ln = (i >> 3) & 63, r2i = i >> 9;
            int ct = r2i & 3, kt = r2i >> 2;
            int k = kt * 32 + ((ln >> 4) << 3) + j;   // 0..127 (concat dim)
            int n = ct * 16 + (ln & 15);
            int t = k >> 6, kk = k & 63;
            float s = 0.f;
            for (int q = 0; q < 64; ++q)
                s += Wc[((size_t)t * 64 + kk) * 64 + q] * Wm[(size_t)(t * 64 + q) * 64 + n];
            mixf_pk[i] = f2b(s);
        }
        for (int i = idx; i < 64; i += stride) {
            float s = bm[i];
            for (int q = 0; q < 64; ++q)
                s += bc_g[q] * Wm[(size_t)q * 64 + i] + bc_g[64 + q] * Wm[(size_t)(64 + q) * 64 + i];
            bfused[i] = s;
        }
    }
}

// ---------------------------------------------------------------------------
// Scan 1/3 over bcnt (137,984 bucket-major counts), IN-PLACE safe: each
// block reads its own 2048 range fully (barrier) before writing it.
// ---------------------------------------------------------------------------
__global__ __launch_bounds__(256) void k_scan1(const int* __restrict__ cnt,
                                               int* __restrict__ off,
                                               int* __restrict__ bsum) {
    __shared__ int s[256];
    int base = blockIdx.x * 2048 + threadIdx.x * 8;
    int v[8];
    int tsum = 0;
#pragma unroll
    for (int j = 0; j < 8; ++j) {
        int g = base + j;
        v[j] = (g < TOTB) ? cnt[g] : 0;
        tsum += v[j];
    }
    s[threadIdx.x] = tsum;
    __syncthreads();
    for (int o = 1; o < 256; o <<= 1) {
        int t = (threadIdx.x >= o) ? s[threadIdx.x - o] : 0;
        __syncthreads();
        s[threadIdx.x] += t;
        __syncthreads();
    }
    int run = s[threadIdx.x] - tsum;
#pragma unroll
    for (int j = 0; j < 8; ++j) {
        int g = base + j;
        if (g < TOTB) off[g] = run;
        run += v[j];
    }
    if (threadIdx.x == 255) bsum[blockIdx.x] = s[255];
}

__global__ __launch_bounds__(1024) void k_scan2(int* __restrict__ bsum) {
    __shared__ int s[1024];
    int tid = threadIdx.x;
    int v = (tid < SCANB) ? bsum[tid] : 0;
    s[tid] = v;
    __syncthreads();
    for (int o = 1; o < 1024; o <<= 1) {
        int t = (tid >= o) ? s[tid - o] : 0;
        __syncthreads();
        s[tid] += t;
        __syncthreads();
    }
    if (tid < SCANB) bsum[tid] = s[tid] - v;
}

__global__ __launch_bounds__(256) void k_scan3(int* __restrict__ off,
                                               const int* __restrict__ bsum) {
    int base = blockIdx.x * 2048 + threadIdx.x * 8;
    int add = bsum[blockIdx.x];
#pragma unroll
    for (int j = 0; j < 8; ++j) {
        int g = base + j;
        if (g < TOTB) off[g] += add;
    }
    if (blockIdx.x == 0 && threadIdx.x == 0) off[TOTB] = 2 * N_EDGES;  // sentinel
}

// ---------------------------------------------------------------------------
// Bucket-sort pass C: ATOMIC-FREE scatter into bucket-major pairs array.
// pos = bbase[bucket][block] + rank. Items from one block to one bucket are
// CONSECUTIVE -> multi-item runs, far less write amplification than the old
// per-segment scatter. pairs[pos] = (seg, payload).
// ---------------------------------------------------------------------------
__global__ __launch_bounds__(256) void k_bscatter(const int* __restrict__ node_idx,
                                                  const int* __restrict__ hedge_idx,
                                                  const int* __restrict__ attr,
                                                  const uint* __restrict__ rk12,
                                                  const int* __restrict__ bbase,
                                                  int2* __restrict__ pairs) {
    int b = blockIdx.x, tid = threadIdx.x;
    int e0 = b * EPB;
    for (int it = 0; it < EPB / 256; ++it) {
        int e = e0 + it * 256 + tid;
        if (e < N_EDGES) {
            int t = attr[e], n = node_idx[e], h = hedge_idx[e];
            int s1 = t * N_HEDGES + h;
            int s2 = HSEG + t * N_NODES + n;
            int b1 = s1 >> 7;
            int b2 = NHB + ((s2 - HSEG) >> 9);
            uint rk = rk12[e];
            int p1 = bbase[b1 * NBLK_A + b] + (int)(rk & 0xFFFF);
            int p2 = bbase[b2 * NBLK_A + b] + (int)(rk >> 16);
            pairs[p1] = make_int2(s1, n);
            pairs[p2] = make_int2(s2, t * N_HEDGES + h);
        }
    }
}

// ---------------------------------------------------------------------------
// Bucket-sort pass D: one block per bucket. LDS per-segment count+rank
// (sweep 1), LDS exclusive scan over <=512 segments, emit dense CSR off[]
// and segment-sorted sortedAll (sweep 2, re-read hits own-XCD L2).
// ---------------------------------------------------------------------------
__global__ __launch_bounds__(256) void k_bfinal(const int* __restrict__ bbase,
                                                const int2* __restrict__ pairs,
                                                int* __restrict__ off,
                                                int* __restrict__ sortedAll) {
    __shared__ int scnt[512];
    __shared__ int exs[512];
    __shared__ int ssum[256];
    __shared__ unsigned short rk[RKCAP];
    int bucket = blockIdx.x, tid = threadIdx.x;
    int seg_first, nseg;
    if (bucket < NHB) {
        seg_first = bucket << 7;
        nseg = min(128, HSEG - seg_first);
    } else {
        int bi = bucket - NHB;
        seg_first = HSEG + (bi << 9);
        nseg = min(512, MSEG - seg_first);
    }
    int bstart = bbase[bucket * NBLK_A];
    int bend = bbase[(bucket + 1) * NBLK_A];   // sentinel covers last bucket
    for (int i = tid; i < 512; i += 256) scnt[i] = 0;
    __syncthreads();
    for (int i = bstart + tid; i < bend; i += 256) {
        int li = i - bstart;
        int key = pairs[i].x;
        int r = atomicAdd(&scnt[key - seg_first], 1);
        if (li < RKCAP) rk[li] = (unsigned short)r;
    }
    __syncthreads();
    int a0 = (2 * tid < nseg) ? scnt[2 * tid] : 0;
    int a1 = (2 * tid + 1 < nseg) ? scnt[2 * tid + 1] : 0;
    ssum[tid] = a0 + a1;
    __syncthreads();
    for (int o = 1; o < 256; o <<= 1) {
        int t = (tid >= o) ? ssum[tid - o] : 0;
        __syncthreads();
        ssum[tid] += t;
        __syncthreads();
    }
    int pb = ssum[tid] - (a0 + a1);
    exs[2 * tid] = pb;
    exs[2 * tid + 1] = pb + a0;
    if (2 * tid < nseg) off[seg_first + 2 * tid] = bstart + pb;
    if (2 * tid + 1 < nseg) off[seg_first + 2 * tid + 1] = bstart + pb + a0;
    if (bucket == NBUCK - 1 && tid == 0) off[MSEG] = 2 * N_EDGES;
    __syncthreads();
    for (int i = bstart + tid; i < bend; i += 256) {
        int li = i - bstart;
        if (li < RKCAP) {
            int2 pr = pairs[i];
            int pos = bstart + exs[pr.x - seg_first] + (int)rk[li];
            sortedAll[pos] = pr.y;
        }
    }
}

// ---------------------------------------------------------------------------
// Quarter-per-segment gather (round-5 proven form): contiguous run per
// segment; 8-lane half-groups, uint4 row reads, shfl_xor(8) combine.
// ---------------------------------------------------------------------------
__device__ __forceinline__ void seg_gather(const int* __restrict__ off,
                                           const int* __restrict__ sortedAll,
                                           const bf16* __restrict__ rows,
                                           int seg0, int lane,
                                           float acc[8], int* total) {
    int q = lane >> 4, l16 = lane & 15;
    int ov = 0;
    if (lane < 5) ov = off[seg0 + lane];   // 4 consecutive segs: begs+ends
    int myb = __shfl(ov, q);
    int mye = __shfl(ov, q + 1);
#pragma unroll
    for (int j = 0; j < 8; ++j) acc[j] = 0.f;
    for (int i = myb + (l16 >> 3); i < mye; i += 2) {
        int idx = sortedAll[i];            // broadcast within 8-lane group
        uint4 v = *(const uint4*)(rows + (size_t)idx * 64 + (l16 & 7) * 8);
        acc[0] += __uint_as_float(v.x << 16);
        acc[1] += __uint_as_float(v.x & 0xffff0000u);
        acc[2] += __uint_as_float(v.y << 16);
        acc[3] += __uint_as_float(v.y & 0xffff0000u);
        acc[4] += __uint_as_float(v.z << 16);
        acc[5] += __uint_as_float(v.z & 0xffff0000u);
        acc[6] += __uint_as_float(v.w << 16);
        acc[7] += __uint_as_float(v.w & 0xffff0000u);
    }
#pragma unroll
    for (int j = 0; j < 8; ++j) acc[j] += __shfl_xor(acc[j], 8);
    *total = mye - myb;
}

// CSR node->hedge: ef_raw[t][h] = (1/B) * sum xb rows (RAW x, no weights).
__global__ __launch_bounds__(256) void k_ef2(const int* __restrict__ off,
                                             const int* __restrict__ sortedAll,
                                             const bf16* __restrict__ xb,
                                             bf16* __restrict__ ef16) {
    int wid = threadIdx.x >> 6, lane = threadIdx.x & 63;
    int seg0 = (blockIdx.x * 4 + wid) * 4;
    if (seg0 >= HSEG) return;
    float acc[8];
    int tot;
    seg_gather(off, sortedAll, xb, seg0, lane, acc, &tot);
    float scale = tot > 0 ? 1.0f / (float)tot : 0.f;
    int q = lane >> 4, l16 = lane & 15;
    if (l16 < 8) {
        int s = seg0 + q;
        uint4 w;
        w.x = pk2(acc[0] * scale, acc[1] * scale);
        w.y = pk2(acc[2] * scale, acc[3] * scale);
        w.z = pk2(acc[4] * scale, acc[5] * scale);
        w.w = pk2(acc[6] * scale, acc[7] * scale);
        *(uint4*)(ef16 + (size_t)s * 64 + l16 * 8) = w;
    }
}

// CSR hedge->node: agg[t][n] = (1/D) * sum ef_raw rows.
__global__ __launch_bounds__(256) void k_no2(const int* __restrict__ off,
                                             const int* __restrict__ sortedAll,
                                             const bf16* __restrict__ ef16,
                                             bf16* __restrict__ agg16) {
    int wid = threadIdx.x >> 6, lane = threadIdx.x & 63;
    int j0 = (blockIdx.x * 4 + wid) * 4;
    if (j0 >= NSEG) return;
    float acc[8];
    int tot;
    seg_gather(off, sortedAll, ef16, HSEG + j0, lane, acc, &tot);
    float scale = tot > 0 ? 1.0f / (float)tot : 0.f;
    int q = lane >> 4, l16 = lane & 15;
    if (l16 < 8) {
        int j = j0 + q;
        uint4 w;
        w.x = pk2(acc[0] * scale, acc[1] * scale);
        w.y = pk2(acc[2] * scale, acc[3] * scale);
        w.z = pk2(acc[4] * scale, acc[5] * scale);
        w.w = pk2(acc[6] * scale, acc[7] * scale);
        *(uint4*)(agg16 + (size_t)j * 64 + l16 * 8) = w;
    }
}

// ---------------------------------------------------------------------------
// FUSED mix+GRU (unchanged — passed rounds 4-6).
// ---------------------------------------------------------------------------
#define GRU_TILES (N_NODES / 16)
__global__ __launch_bounds__(256) void k_mixgru(const bf16* __restrict__ gru_pk,
                                                const bf16* __restrict__ mixf_pk,
                                                const float* __restrict__ bfused,
                                                const bf16* __restrict__ agg16,
                                                const float* __restrict__ h_prev,
                                                const float* __restrict__ bih_g,
                                                const float* __restrict__ bhh_g,
                                                const float* __restrict__ Wro_g,
                                                const float* __restrict__ bro_g,
                                                float* __restrict__ out_h,
                                                float* __restrict__ out_o) {
    __shared__ __align__(16) bf16 Wpk[GRU_PK];      // 48 KB
    __shared__ __align__(16) bf16 Wmx[MIX_PK];      // 16 KB
    __shared__ __align__(16) bf16 bounce[4 * 1024]; // 4 waves x 16x64 bf16 = 8 KB
    {
        const bf16x8* src = (const bf16x8*)gru_pk;
        bf16x8* dst = (bf16x8*)Wpk;
        for (int i = threadIdx.x; i < GRU_PK / 8; i += 256) dst[i] = src[i];
        const bf16x8* src2 = (const bf16x8*)mixf_pk;
        bf16x8* dst2 = (bf16x8*)Wmx;
        for (int i = threadIdx.x; i < MIX_PK / 8; i += 256) dst2[i] = src2[i];
    }
    __syncthreads();

    int wid = threadIdx.x >> 6, lane = threadIdx.x & 63;
    int quad = lane >> 4, l16 = lane & 15;
    bf16* bnc = &bounce[wid * 1024];

    float bmv[4];
#pragma unroll
    for (int ct = 0; ct < 4; ++ct) bmv[ct] = bfused[ct * 16 + l16];

    float br_c[4], bz_c[4], bin_c[4], bhn_c[4], wv[4][3];
#pragma unroll
    for (int cc = 0; cc < 4; ++cc) {
        int col = cc * 16 + l16;
        br_c[cc] = bih_g[col] + bhh_g[col];
        bz_c[cc] = bih_g[64 + col] + bhh_g[64 + col];
        bin_c[cc] = bih_g[128 + col];
        bhn_c[cc] = bhh_g[128 + col];
        wv[cc][0] = Wro_g[col * 64 + 0];
        wv[cc][1] = Wro_g[col * 64 + 1];
        wv[cc][2] = Wro_g[col * 64 + 2];
    }
    float bro0 = bro_g[0], bro1 = bro_g[1], bro2 = bro_g[2];

    int wave = blockIdx.x * 4 + wid;
    int n_waves = gridDim.x * 4;

    for (int tile = wave; tile < GRU_TILES; tile += n_waves) {
        int row0 = tile * 16;
        int arow = row0 + l16;

        // ---- mix ----
        bf16x8 af[4];
#pragma unroll
        for (int kt = 0; kt < 4; ++kt) {
            const bf16* src = (kt < 2)
                ? agg16 + (size_t)arow * 64 + kt * 32 + quad * 8
                : agg16 + ((size_t)N_NODES + arow) * 64 + (kt - 2) * 32 + quad * 8;
            af[kt] = *(const bf16x8*)src;
        }
#define LDBM(kt, ct) (*(const bf16x8*)&Wmx[(((kt)*4 + (ct)) * 64 + lane) * 8])
#pragma unroll
        for (int ct = 0; ct < 4; ++ct) {
            f32x4 acc = {bmv[ct], bmv[ct], bmv[ct], bmv[ct]};
#pragma unroll
            for (int kt = 0; kt < 4; ++kt)
                acc = __builtin_amdgcn_mfma_f32_16x16x32_bf16(af[kt], LDBM(kt, ct), acc, 0, 0, 0);
            // D-layout store into per-wave bounce, chunk-XOR swizzled.
#pragma unroll
            for (int rg = 0; rg < 4; ++rg) {
                int r = quad * 4 + rg;                       // local row
                int chunk = ct * 2 + (l16 >> 3);             // 8-col chunk
                int cs = chunk ^ (r & 7);                    // swizzled
                bnc[r * 64 + cs * 8 + (l16 & 7)] = f2b(fmaxf(acc[rg], 0.f));
            }
        }
#undef LDBM
        asm volatile("s_waitcnt lgkmcnt(0)" ::: "memory");
        __builtin_amdgcn_sched_barrier(0);

        // ---- re-read as A-fragments (row l16, chunks quad / quad+4) ----
        bf16x8 ha0 = *(const bf16x8*)&bnc[l16 * 64 + (quad ^ (l16 & 7)) * 8];
        bf16x8 ha1 = *(const bf16x8*)&bnc[l16 * 64 + ((quad + 4) ^ (l16 & 7)) * 8];

        const float* pp = h_prev + (size_t)arow * 64 + quad * 8;
        bf16x8 pa0 = pack8(*(const float4*)pp, *(const float4*)(pp + 4));
        bf16x8 pa1 = pack8(*(const float4*)(pp + 32), *(const float4*)(pp + 36));

        float p[4][3];
#pragma unroll
        for (int rg = 0; rg < 4; ++rg) p[rg][0] = p[rg][1] = p[rg][2] = 0.f;

#pragma unroll
        for (int cc = 0; cc < 4; ++cc) {
#define LDB(mat, kt, ct) (*(const bf16x8*)&Wpk[((((mat)*2 + (kt)) * 12 + (ct)) * 64 + lane) * 8])
            f32x4 rs = {br_c[cc], br_c[cc], br_c[cc], br_c[cc]};
            f32x4 zs = {bz_c[cc], bz_c[cc], bz_c[cc], bz_c[cc]};
            f32x4 gin = {bin_c[cc], bin_c[cc], bin_c[cc], bin_c[cc]};
            f32x4 ghn = {bhn_c[cc], bhn_c[cc], bhn_c[cc], bhn_c[cc]};
            rs = __builtin_amdgcn_mfma_f32_16x16x32_bf16(ha0, LDB(0, 0, cc), rs, 0, 0, 0);
            rs = __builtin_amdgcn_mfma_f32_16x16x32_bf16(ha1, LDB(0, 1, cc), rs, 0, 0, 0);
            rs = __builtin_amdgcn_mfma_f32_16x16x32_bf16(pa0, LDB(1, 0, cc), rs, 0, 0, 0);
            rs = __builtin_amdgcn_mfma_f32_16x16x32_bf16(pa1, LDB(1, 1, cc), rs, 0, 0, 0);
            zs = __builtin_amdgcn_mfma_f32_16x16x32_bf16(ha0, LDB(0, 0, cc + 4), zs, 0, 0, 0);
            zs = __builtin_amdgcn_mfma_f32_16x16x32_bf16(ha1, LDB(0, 1, cc + 4), zs, 0, 0, 0);
            zs = __builtin_amdgcn_mfma_f32_16x16x32_bf16(pa0, LDB(1, 0, cc + 4), zs, 0, 0, 0);
            zs = __builtin_amdgcn_mfma_f32_16x16x32_bf16(pa1, LDB(1, 1, cc + 4), zs, 0, 0, 0);
            gin = __builtin_amdgcn_mfma_f32_16x16x32_bf16(ha0, LDB(0, 0, cc + 8), gin, 0, 0, 0);
            gin = __builtin_amdgcn_mfma_f32_16x16x32_bf16(ha1, LDB(0, 1, cc + 8), gin, 0, 0, 0);
            ghn = __builtin_amdgcn_mfma_f32_16x16x32_bf16(pa0, LDB(1, 0, cc + 8), ghn, 0, 0, 0);
            ghn = __builtin_amdgcn_mfma_f32_16x16x32_bf16(pa1, LDB(1, 1, cc + 8), ghn, 0, 0, 0);
#undef LDB
#pragma unroll
            for (int rg = 0; rg < 4; ++rg) {
                int row = row0 + quad * 4 + rg;
                float pv = h_prev[(size_t)row * 64 + cc * 16 + l16];
                float rr = fast_sigmoid(rs[rg]);
                float zz = fast_sigmoid(zs[rg]);
                float nn = fast_tanh(gin[rg] + rr * ghn[rg]);
                float hn = (1.f - zz) * nn + zz * pv;
                out_h[(size_t)row * 64 + cc * 16 + l16] = hn;
                p[rg][0] += hn * wv[cc][0];
                p[rg][1] += hn * wv[cc][1];
                p[rg][2] += hn * wv[cc][2];
            }
        }
#pragma unroll
        for (int rg = 0; rg < 4; ++rg) {
#pragma unroll
            for (int m = 1; m < 16; m <<= 1) {
                p[rg][0] += __shfl_xor(p[rg][0], m);
                p[rg][1] += __shfl_xor(p[rg][1], m);
                p[rg][2] += __shfl_xor(p[rg][2], m);
            }
        }
        if (l16 == 0) {
#pragma unroll
            for (int rg = 0; rg < 4; ++rg) {
                int row = row0 + quad * 4 + rg;
                out_o[(size_t)row * 3 + 0] = p[rg][0] + bro0;
                out_o[(size_t)row * 3 + 1] = p[rg][1] + bro1;
                out_o[(size_t)row * 3 + 2] = p[rg][2] + bro2;
            }
        }
    }
}

extern "C" void kernel_launch(void* const* d_in, const int* in_sizes, int n_in,
                              void* d_out, int out_size, void* d_ws, size_t ws_size,
                              hipStream_t stream) {
    const float* x        = (const float*)d_in[0];
    const float* h_prev   = (const float*)d_in[1];
    const int* node_idx   = (const int*)d_in[2];
    const int* hedge_idx  = (const int*)d_in[3];
    const int* edge_attr  = (const int*)d_in[4];
    const float* W_conv   = (const float*)d_in[5];
    const float* b_conv   = (const float*)d_in[6];
    const float* W_mix    = (const float*)d_in[7];
    const float* b_mix    = (const float*)d_in[8];
    const float* W_ih     = (const float*)d_in[9];
    const float* W_hh     = (const float*)d_in[10];
    const float* b_ih     = (const float*)d_in[11];
    const float* b_hh     = (const float*)d_in[12];
    const float* W_ro     = (const float*)d_in[13];
    const float* b_ro     = (const float*)d_in[14];

    char* p = (char*)d_ws;
    auto alloc = [&](size_t bytes) {
        char* r = p;
        p += (bytes + 63) & ~(size_t)63;
        return r;
    };
    // Region A (25.6MB): bucket-sort scratch {pairs 12.8MB, rk12 3.2MB,
    // bcnt 0.55MB, bsum 4KB} — all dead after k_bfinal — overlaid by agg16
    // (first written in k_no2).
    char* regA     = alloc((size_t)2 * N_NODES * 64 * 2);   // 25.6 MB
    int2* pairs    = (int2*)regA;
    uint* rk12     = (uint*)(pairs + 2 * N_EDGES);
    int* bcnt      = (int*)(rk12 + N_EDGES);
    int* bsum      = bcnt + TOTB + 1;
    bf16* agg16    = (bf16*)regA;
    int* off       = (int*)alloc((size_t)(MSEG + 1) * 4);   // live CSR ptrs
    int* sortedAll = (int*)alloc((size_t)2 * N_EDGES * 4);
    bf16* xb       = (bf16*)alloc((size_t)N_NODES * 64 * 2);
    bf16* ef16     = (bf16*)alloc((size_t)HSEG * 64 * 2);
    bf16* gru_pk   = (bf16*)alloc((size_t)GRU_PK * 2);
    bf16* mixf_pk  = (bf16*)alloc((size_t)MIX_PK * 2);
    float* bfused  = (float*)alloc(64 * 4);

    float* out_h = (float*)d_out;
    float* out_o = out_h + (size_t)N_NODES * 64;

    k_front<<<NBLK_A + CAST_BLOCKS + PACK_BLOCKS, 256, 0, stream>>>(
        node_idx, hedge_idx, edge_attr, rk12, bcnt, x, xb,
        W_conv, W_mix, b_conv, b_mix, W_ih, W_hh, gru_pk, mixf_pk, bfused);
    k_scan1<<<SCANB, 256, 0, stream>>>(bcnt, bcnt, bsum);   // in-place
    k_scan2<<<1, 1024, 0, stream>>>(bsum);
    k_scan3<<<SCANB, 256, 0, stream>>>(bcnt, bsum);
    k_bscatter<<<NBLK_A, 256, 0, stream>>>(node_idx, hedge_idx, edge_attr,
                                           rk12, bcnt, pairs);
    k_bfinal<<<NBUCK, 256, 0, stream>>>(bcnt, pairs, off, sortedAll);
    k_ef2<<<HSEG / 16, 256, 0, stream>>>(off, sortedAll, xb, ef16);
    k_no2<<<NSEG / 16, 256, 0, stream>>>(off, sortedAll, ef16, agg16);
    k_mixgru<<<512, 256, 0, stream>>>(gru_pk, mixf_pk, bfused, agg16, h_prev,
                                      b_ih, b_hh, W_ro, b_ro, out_h, out_o);
}

// Round 8
// 253.805 us; speedup vs baseline: 1.3190x; 1.0190x over previous
//
#include <hip/hip_runtime.h>
#include <hip/hip_bf16.h>

#define N_NODES 100000
#define N_HEDGES 20000
#define N_EDGES 800000
#define HSEG (2 * N_HEDGES)            // 40000 hedge segments (t,h)
#define NSEG (2 * N_NODES)             // 200000 node segments (t,n)
#define MSEG (HSEG + NSEG)             // 240000 segments

// Two-level LDS bucket sort geometry:
#define EPB 4096                        // edges per pass-A/C block
#define NBLK_A ((N_EDGES + EPB - 1) / EPB)  // 196
#define NHB 313                         // hedge buckets: 128 segs each
#define NBUCK 704                       // + 391 node buckets: 512 segs each
#define TOTB (NBUCK * NBLK_A)           // 137,984 (bucket-major counts)
#define SCANB ((TOTB + 2047) / 2048)    // 68
#define RKCAP 8192                      // max entries/bucket (mean ~2.3K)

#define CAST_BLOCKS (N_NODES * 64 / 8 / 256)   // 3125
#define PACK_BLOCKS 16

#define MIX_PK  (4 * 4 * 64 * 8)        // 8192 packed bf16 fused-mix weights
#define GRU_PK  (2 * 2 * 12 * 64 * 8)   // 24576 for k_mixgru

typedef __hip_bfloat16 bf16;
typedef __attribute__((ext_vector_type(8))) short bf16x8;
typedef __attribute__((ext_vector_type(4))) float f32x4;

__device__ __forceinline__ bf16 f2b(float v) { return __float2bfloat16(v); }
__device__ __forceinline__ short f2s(float v) {
    bf16 b = __float2bfloat16(v);
    return *reinterpret_cast<short*>(&b);
}
__device__ __forceinline__ uint pk2(float a, float b) {
    return (uint)(unsigned short)f2s(a) | ((uint)(unsigned short)f2s(b) << 16);
}
__device__ __forceinline__ bf16x8 pack8(float4 a, float4 b) {
    bf16x8 r = {f2s(a.x), f2s(a.y), f2s(a.z), f2s(a.w),
                f2s(b.x), f2s(b.y), f2s(b.z), f2s(b.w)};
    return r;
}
__device__ __forceinline__ float fast_sigmoid(float x) {
    return __builtin_amdgcn_rcpf(1.f + __expf(-x));
}
__device__ __forceinline__ float fast_tanh(float x) {
    return 1.f - 2.f * __builtin_amdgcn_rcpf(1.f + __expf(2.f * x));
}

// ---------------------------------------------------------------------------
// FRONT kernel, three roles by blockIdx (unchanged from round 7 — passed):
//  [0, NBLK_A)     bucket-sort pass A: LDS histogram, zero global atomics
//  [.., +CAST)     x -> bf16 cast
//  [.., +PACK)     weight packing + conv/mix fusion (Wf = Wc @ Wm_t)
// ---------------------------------------------------------------------------
__global__ __launch_bounds__(256) void k_front(
    const int* __restrict__ node_idx, const int* __restrict__ hedge_idx,
    const int* __restrict__ attr, uint* __restrict__ rk12,
    int* __restrict__ bcnt,
    const float* __restrict__ x, bf16* __restrict__ xb,
    const float* __restrict__ Wc, const float* __restrict__ Wm,
    const float* __restrict__ bc_g, const float* __restrict__ bm,
    const float* __restrict__ Wih, const float* __restrict__ Whh,
    bf16* __restrict__ gru_pk, bf16* __restrict__ mixf_pk,
    float* __restrict__ bfused) {
    __shared__ int bc[NBUCK];
    int b = blockIdx.x;
    int tid = threadIdx.x;
    if (b < NBLK_A) {
        for (int i = tid; i < NBUCK; i += 256) bc[i] = 0;
        __syncthreads();
        int e0 = b * EPB;
        for (int it = 0; it < EPB / 256; ++it) {
            int e = e0 + it * 256 + tid;
            if (e < N_EDGES) {
                int t = attr[e];
                int s1 = t * N_HEDGES + hedge_idx[e];
                int s2 = HSEG + t * N_NODES + node_idx[e];
                int b1 = s1 >> 7;
                int b2 = NHB + ((s2 - HSEG) >> 9);
                int r1 = atomicAdd(&bc[b1], 1);
                int r2 = atomicAdd(&bc[b2], 1);
                rk12[e] = (uint)(r1 & 0xFFFF) | ((uint)r2 << 16);
            }
        }
        __syncthreads();
        for (int i = tid; i < NBUCK; i += 256) bcnt[i * NBLK_A + b] = bc[i];
    } else if (b < NBLK_A + CAST_BLOCKS) {
        size_t i = ((size_t)(b - NBLK_A) * 256 + tid) * 8;
        const float* xp = x + i;
        float4 a = *(const float4*)xp;
        float4 bb = *(const float4*)(xp + 4);
        *(bf16x8*)(xb + i) = pack8(a, bb);
    } else {
        int idx = (b - NBLK_A - CAST_BLOCKS) * 256 + tid;
        int stride = PACK_BLOCKS * 256;
        for (int i = idx; i < GRU_PK; i += stride) {
            int j = i & 7;
            int r = i >> 3;
            int ln = r & 63;
            int r2i = r >> 6;
            int ct = r2i % 12;
            int r3 = r2i / 12;
            int kt = r3 & 1;
            int mat = r3 >> 1;
            int k = kt * 32 + ((ln >> 4) << 3) + j;
            int n = ct * 16 + (ln & 15);
            float v = mat == 0 ? Wih[k * 192 + n] : Whh[k * 192 + n];
            gru_pk[i] = f2b(v);
        }
        for (int i = idx; i < MIX_PK; i += stride) {
            int j = i & 7, ln = (i >> 3) & 63, r2i = i >> 9;
            int ct = r2i & 3, kt = r2i >> 2;
            int k = kt * 32 + ((ln >> 4) << 3) + j;   // 0..127 (concat dim)
            int n = ct * 16 + (ln & 15);
            int t = k >> 6, kk = k & 63;
            float s = 0.f;
            for (int q = 0; q < 64; ++q)
                s += Wc[((size_t)t * 64 + kk) * 64 + q] * Wm[(size_t)(t * 64 + q) * 64 + n];
            mixf_pk[i] = f2b(s);
        }
        for (int i = idx; i < 64; i += stride) {
            float s = bm[i];
            for (int q = 0; q < 64; ++q)
                s += bc_g[q] * Wm[(size_t)q * 64 + i] + bc_g[64 + q] * Wm[(size_t)(64 + q) * 64 + i];
            bfused[i] = s;
        }
    }
}

// ---------------------------------------------------------------------------
// Scan 1/3 over bcnt, IN-PLACE safe (block reads its range before writing).
// ---------------------------------------------------------------------------
__global__ __launch_bounds__(256) void k_scan1(const int* __restrict__ cnt,
                                               int* __restrict__ off,
                                               int* __restrict__ bsum) {
    __shared__ int s[256];
    int base = blockIdx.x * 2048 + threadIdx.x * 8;
    int v[8];
    int tsum = 0;
#pragma unroll
    for (int j = 0; j < 8; ++j) {
        int g = base + j;
        v[j] = (g < TOTB) ? cnt[g] : 0;
        tsum += v[j];
    }
    s[threadIdx.x] = tsum;
    __syncthreads();
    for (int o = 1; o < 256; o <<= 1) {
        int t = (threadIdx.x >= o) ? s[threadIdx.x - o] : 0;
        __syncthreads();
        s[threadIdx.x] += t;
        __syncthreads();
    }
    int run = s[threadIdx.x] - tsum;
#pragma unroll
    for (int j = 0; j < 8; ++j) {
        int g = base + j;
        if (g < TOTB) off[g] = run;
        run += v[j];
    }
    if (threadIdx.x == 255) bsum[blockIdx.x] = s[255];
}

__global__ __launch_bounds__(1024) void k_scan2(int* __restrict__ bsum) {
    __shared__ int s[1024];
    int tid = threadIdx.x;
    int v = (tid < SCANB) ? bsum[tid] : 0;
    s[tid] = v;
    __syncthreads();
    for (int o = 1; o < 1024; o <<= 1) {
        int t = (tid >= o) ? s[tid - o] : 0;
        __syncthreads();
        s[tid] += t;
        __syncthreads();
    }
    if (tid < SCANB) bsum[tid] = s[tid] - v;
}

__global__ __launch_bounds__(256) void k_scan3(int* __restrict__ off,
                                               const int* __restrict__ bsum) {
    int base = blockIdx.x * 2048 + threadIdx.x * 8;
    int add = bsum[blockIdx.x];
#pragma unroll
    for (int j = 0; j < 8; ++j) {
        int g = base + j;
        if (g < TOTB) off[g] += add;
    }
    if (blockIdx.x == 0 && threadIdx.x == 0) off[TOTB] = 2 * N_EDGES;  // sentinel
}

// ---------------------------------------------------------------------------
// Bucket-sort pass C: ATOMIC-FREE scatter into bucket-major pairs array.
// ---------------------------------------------------------------------------
__global__ __launch_bounds__(256) void k_bscatter(const int* __restrict__ node_idx,
                                                  const int* __restrict__ hedge_idx,
                                                  const int* __restrict__ attr,
                                                  const uint* __restrict__ rk12,
                                                  const int* __restrict__ bbase,
                                                  int2* __restrict__ pairs) {
    int b = blockIdx.x, tid = threadIdx.x;
    int e0 = b * EPB;
    for (int it = 0; it < EPB / 256; ++it) {
        int e = e0 + it * 256 + tid;
        if (e < N_EDGES) {
            int t = attr[e], n = node_idx[e], h = hedge_idx[e];
            int s1 = t * N_HEDGES + h;
            int s2 = HSEG + t * N_NODES + n;
            int b1 = s1 >> 7;
            int b2 = NHB + ((s2 - HSEG) >> 9);
            uint rk = rk12[e];
            int p1 = bbase[b1 * NBLK_A + b] + (int)(rk & 0xFFFF);
            int p2 = bbase[b2 * NBLK_A + b] + (int)(rk >> 16);
            pairs[p1] = make_int2(s1, n);
            pairs[p2] = make_int2(s2, t * N_HEDGES + h);
        }
    }
}

// ---------------------------------------------------------------------------
// Bucket-sort pass D: one block per bucket -> dense CSR off[] + sortedAll.
// ---------------------------------------------------------------------------
__global__ __launch_bounds__(256) void k_bfinal(const int* __restrict__ bbase,
                                                const int2* __restrict__ pairs,
                                                int* __restrict__ off,
                                                int* __restrict__ sortedAll) {
    __shared__ int scnt[512];
    __shared__ int exs[512];
    __shared__ int ssum[256];
    __shared__ unsigned short rk[RKCAP];
    int bucket = blockIdx.x, tid = threadIdx.x;
    int seg_first, nseg;
    if (bucket < NHB) {
        seg_first = bucket << 7;
        nseg = min(128, HSEG - seg_first);
    } else {
        int bi = bucket - NHB;
        seg_first = HSEG + (bi << 9);
        nseg = min(512, MSEG - seg_first);
    }
    int bstart = bbase[bucket * NBLK_A];
    int bend = bbase[(bucket + 1) * NBLK_A];   // sentinel covers last bucket
    for (int i = tid; i < 512; i += 256) scnt[i] = 0;
    __syncthreads();
    for (int i = bstart + tid; i < bend; i += 256) {
        int li = i - bstart;
        int key = pairs[i].x;
        int r = atomicAdd(&scnt[key - seg_first], 1);
        if (li < RKCAP) rk[li] = (unsigned short)r;
    }
    __syncthreads();
    int a0 = (2 * tid < nseg) ? scnt[2 * tid] : 0;
    int a1 = (2 * tid + 1 < nseg) ? scnt[2 * tid + 1] : 0;
    ssum[tid] = a0 + a1;
    __syncthreads();
    for (int o = 1; o < 256; o <<= 1) {
        int t = (tid >= o) ? ssum[tid - o] : 0;
        __syncthreads();
        ssum[tid] += t;
        __syncthreads();
    }
    int pb = ssum[tid] - (a0 + a1);
    exs[2 * tid] = pb;
    exs[2 * tid + 1] = pb + a0;
    if (2 * tid < nseg) off[seg_first + 2 * tid] = bstart + pb;
    if (2 * tid + 1 < nseg) off[seg_first + 2 * tid + 1] = bstart + pb + a0;
    if (bucket == NBUCK - 1 && tid == 0) off[MSEG] = 2 * N_EDGES;
    __syncthreads();
    for (int i = bstart + tid; i < bend; i += 256) {
        int li = i - bstart;
        if (li < RKCAP) {
            int2 pr = pairs[i];
            int pos = bstart + exs[pr.x - seg_first] + (int)rk[li];
            sortedAll[pos] = pr.y;
        }
    }
}

// ---------------------------------------------------------------------------
// Quarter-per-segment gather, 2-DEEP PIPELINED: each 8-lane half-group keeps
// TWO {idx -> 128B row} dependency chains in flight (stride-4 loop, i and
// i+2) -> 16 outstanding chains per wave vs 8. Tail handles the odd element.
// shfl_xor(8) combines halves; lanes 0..7 of each quarter store 16B.
// ---------------------------------------------------------------------------
__device__ __forceinline__ void seg_gather(const int* __restrict__ off,
                                           const int* __restrict__ sortedAll,
                                           const bf16* __restrict__ rows,
                                           int seg0, int lane,
                                           float acc[8], int* total) {
    int q = lane >> 4, l16 = lane & 15;
    int ov = 0;
    if (lane < 5) ov = off[seg0 + lane];   // 4 consecutive segs: begs+ends
    int myb = __shfl(ov, q);
    int mye = __shfl(ov, q + 1);
#pragma unroll
    for (int j = 0; j < 8; ++j) acc[j] = 0.f;
    int cb = (l16 & 7) * 8;                // this lane's 16B column chunk
    int i = myb + (l16 >> 3);
    for (; i + 2 < mye; i += 4) {
        int idx0 = sortedAll[i];
        int idx1 = sortedAll[i + 2];
        uint4 v0 = *(const uint4*)(rows + (size_t)idx0 * 64 + cb);
        uint4 v1 = *(const uint4*)(rows + (size_t)idx1 * 64 + cb);
        acc[0] += __uint_as_float(v0.x << 16);
        acc[1] += __uint_as_float(v0.x & 0xffff0000u);
        acc[2] += __uint_as_float(v0.y << 16);
        acc[3] += __uint_as_float(v0.y & 0xffff0000u);
        acc[4] += __uint_as_float(v0.z << 16);
        acc[5] += __uint_as_float(v0.z & 0xffff0000u);
        acc[6] += __uint_as_float(v0.w << 16);
        acc[7] += __uint_as_float(v0.w & 0xffff0000u);
        acc[0] += __uint_as_float(v1.x << 16);
        acc[1] += __uint_as_float(v1.x & 0xffff0000u);
        acc[2] += __uint_as_float(v1.y << 16);
        acc[3] += __uint_as_float(v1.y & 0xffff0000u);
        acc[4] += __uint_as_float(v1.z << 16);
        acc[5] += __uint_as_float(v1.z & 0xffff0000u);
        acc[6] += __uint_as_float(v1.w << 16);
        acc[7] += __uint_as_float(v1.w & 0xffff0000u);
    }
    if (i < mye) {
        int idx = sortedAll[i];
        uint4 v = *(const uint4*)(rows + (size_t)idx * 64 + cb);
        acc[0] += __uint_as_float(v.x << 16);
        acc[1] += __uint_as_float(v.x & 0xffff0000u);
        acc[2] += __uint_as_float(v.y << 16);
        acc[3] += __uint_as_float(v.y & 0xffff0000u);
        acc[4] += __uint_as_float(v.z << 16);
        acc[5] += __uint_as_float(v.z & 0xffff0000u);
        acc[6] += __uint_as_float(v.w << 16);
        acc[7] += __uint_as_float(v.w & 0xffff0000u);
    }
#pragma unroll
    for (int j = 0; j < 8; ++j) acc[j] += __shfl_xor(acc[j], 8);
    *total = mye - myb;
}

// CSR node->hedge: ef_raw[t][h] = (1/B) * sum xb rows (RAW x, no weights).
__global__ __launch_bounds__(256) void k_ef2(const int* __restrict__ off,
                                             const int* __restrict__ sortedAll,
                                             const bf16* __restrict__ xb,
                                             bf16* __restrict__ ef16) {
    int wid = threadIdx.x >> 6, lane = threadIdx.x & 63;
    int seg0 = (blockIdx.x * 4 + wid) * 4;
    if (seg0 >= HSEG) return;
    float acc[8];
    int tot;
    seg_gather(off, sortedAll, xb, seg0, lane, acc, &tot);
    float scale = tot > 0 ? 1.0f / (float)tot : 0.f;
    int q = lane >> 4, l16 = lane & 15;
    if (l16 < 8) {
        int s = seg0 + q;
        uint4 w;
        w.x = pk2(acc[0] * scale, acc[1] * scale);
        w.y = pk2(acc[2] * scale, acc[3] * scale);
        w.z = pk2(acc[4] * scale, acc[5] * scale);
        w.w = pk2(acc[6] * scale, acc[7] * scale);
        *(uint4*)(ef16 + (size_t)s * 64 + l16 * 8) = w;
    }
}

// CSR hedge->node: agg[t][n] = (1/D) * sum ef_raw rows.
__global__ __launch_bounds__(256) void k_no2(const int* __restrict__ off,
                                             const int* __restrict__ sortedAll,
                                             const bf16* __restrict__ ef16,
                                             bf16* __restrict__ agg16) {
    int wid = threadIdx.x >> 6, lane = threadIdx.x & 63;
    int j0 = (blockIdx.x * 4 + wid) * 4;
    if (j0 >= NSEG) return;
    float acc[8];
    int tot;
    seg_gather(off, sortedAll, ef16, HSEG + j0, lane, acc, &tot);
    float scale = tot > 0 ? 1.0f / (float)tot : 0.f;
    int q = lane >> 4, l16 = lane & 15;
    if (l16 < 8) {
        int j = j0 + q;
        uint4 w;
        w.x = pk2(acc[0] * scale, acc[1] * scale);
        w.y = pk2(acc[2] * scale, acc[3] * scale);
        w.z = pk2(acc[4] * scale, acc[5] * scale);
        w.w = pk2(acc[6] * scale, acc[7] * scale);
        *(uint4*)(agg16 + (size_t)j * 64 + l16 * 8) = w;
    }
}

// ---------------------------------------------------------------------------
// FUSED mix+GRU — now 512-THREAD blocks (8 waves): LDS 48+16+16 = 80 KB
// -> still 2 blocks/CU, but 16 waves/CU (round-7 counters: 14.8% occupancy,
// MfmaUtil 5.5%, nothing saturated => latency-bound; doubling resident
// waves is the direct fix). VGPR 108 < 128 so 4 waves/SIMD fit. Grid 512.
// ---------------------------------------------------------------------------
#define GRU_TILES (N_NODES / 16)
__global__ __launch_bounds__(512) void k_mixgru(const bf16* __restrict__ gru_pk,
                                                const bf16* __restrict__ mixf_pk,
                                                const float* __restrict__ bfused,
                                                const bf16* __restrict__ agg16,
                                                const float* __restrict__ h_prev,
                                                const float* __restrict__ bih_g,
                                                const float* __restrict__ bhh_g,
                                                const float* __restrict__ Wro_g,
                                                const float* __restrict__ bro_g,
                                                float* __restrict__ out_h,
                                                float* __restrict__ out_o) {
    __shared__ __align__(16) bf16 Wpk[GRU_PK];      // 48 KB
    __shared__ __align__(16) bf16 Wmx[MIX_PK];      // 16 KB
    __shared__ __align__(16) bf16 bounce[8 * 1024]; // 8 waves x 16x64 bf16 = 16 KB
    {
        const bf16x8* src = (const bf16x8*)gru_pk;
        bf16x8* dst = (bf16x8*)Wpk;
        for (int i = threadIdx.x; i < GRU_PK / 8; i += 512) dst[i] = src[i];
        const bf16x8* src2 = (const bf16x8*)mixf_pk;
        bf16x8* dst2 = (bf16x8*)Wmx;
        for (int i = threadIdx.x; i < MIX_PK / 8; i += 512) dst2[i] = src2[i];
    }
    __syncthreads();

    int wid = threadIdx.x >> 6, lane = threadIdx.x & 63;
    int quad = lane >> 4, l16 = lane & 15;
    bf16* bnc = &bounce[wid * 1024];

    float bmv[4];
#pragma unroll
    for (int ct = 0; ct < 4; ++ct) bmv[ct] = bfused[ct * 16 + l16];

    float br_c[4], bz_c[4], bin_c[4], bhn_c[4], wv[4][3];
#pragma unroll
    for (int cc = 0; cc < 4; ++cc) {
        int col = cc * 16 + l16;
        br_c[cc] = bih_g[col] + bhh_g[col];
        bz_c[cc] = bih_g[64 + col] + bhh_g[64 + col];
        bin_c[cc] = bih_g[128 + col];
        bhn_c[cc] = bhh_g[128 + col];
        wv[cc][0] = Wro_g[col * 64 + 0];
        wv[cc][1] = Wro_g[col * 64 + 1];
        wv[cc][2] = Wro_g[col * 64 + 2];
    }
    float bro0 = bro_g[0], bro1 = bro_g[1], bro2 = bro_g[2];

    int wave = blockIdx.x * 8 + wid;
    int n_waves = gridDim.x * 8;

    for (int tile = wave; tile < GRU_TILES; tile += n_waves) {
        int row0 = tile * 16;
        int arow = row0 + l16;

        // ---- mix ----
        bf16x8 af[4];
#pragma unroll
        for (int kt = 0; kt < 4; ++kt) {
            const bf16* src = (kt < 2)
                ? agg16 + (size_t)arow * 64 + kt * 32 + quad * 8
                : agg16 + ((size_t)N_NODES + arow) * 64 + (kt - 2) * 32 + quad * 8;
            af[kt] = *(const bf16x8*)src;
        }
#define LDBM(kt, ct) (*(const bf16x8*)&Wmx[(((kt)*4 + (ct)) * 64 + lane) * 8])
#pragma unroll
        for (int ct = 0; ct < 4; ++ct) {
            f32x4 acc = {bmv[ct], bmv[ct], bmv[ct], bmv[ct]};
#pragma unroll
            for (int kt = 0; kt < 4; ++kt)
                acc = __builtin_amdgcn_mfma_f32_16x16x32_bf16(af[kt], LDBM(kt, ct), acc, 0, 0, 0);
            // D-layout store into per-wave bounce, chunk-XOR swizzled.
#pragma unroll
            for (int rg = 0; rg < 4; ++rg) {
                int r = quad * 4 + rg;                       // local row
                int chunk = ct * 2 + (l16 >> 3);             // 8-col chunk
                int cs = chunk ^ (r & 7);                    // swizzled
                bnc[r * 64 + cs * 8 + (l16 & 7)] = f2b(fmaxf(acc[rg], 0.f));
            }
        }
#undef LDBM
        asm volatile("s_waitcnt lgkmcnt(0)" ::: "memory");
        __builtin_amdgcn_sched_barrier(0);

        // ---- re-read as A-fragments (row l16, chunks quad / quad+4) ----
        bf16x8 ha0 = *(const bf16x8*)&bnc[l16 * 64 + (quad ^ (l16 & 7)) * 8];
        bf16x8 ha1 = *(const bf16x8*)&bnc[l16 * 64 + ((quad + 4) ^ (l16 & 7)) * 8];

        const float* pp = h_prev + (size_t)arow * 64 + quad * 8;
        bf16x8 pa0 = pack8(*(const float4*)pp, *(const float4*)(pp + 4));
        bf16x8 pa1 = pack8(*(const float4*)(pp + 32), *(const float4*)(pp + 36));

        float p[4][3];
#pragma unroll
        for (int rg = 0; rg < 4; ++rg) p[rg][0] = p[rg][1] = p[rg][2] = 0.f;

#pragma unroll
        for (int cc = 0; cc < 4; ++cc) {
#define LDB(mat, kt, ct) (*(const bf16x8*)&Wpk[((((mat)*2 + (kt)) * 12 + (ct)) * 64 + lane) * 8])
            f32x4 rs = {br_c[cc], br_c[cc], br_c[cc], br_c[cc]};
            f32x4 zs = {bz_c[cc], bz_c[cc], bz_c[cc], bz_c[cc]};
            f32x4 gin = {bin_c[cc], bin_c[cc], bin_c[cc], bin_c[cc]};
            f32x4 ghn = {bhn_c[cc], bhn_c[cc], bhn_c[cc], bhn_c[cc]};
            rs = __builtin_amdgcn_mfma_f32_16x16x32_bf16(ha0, LDB(0, 0, cc), rs, 0, 0, 0);
            rs = __builtin_amdgcn_mfma_f32_16x16x32_bf16(ha1, LDB(0, 1, cc), rs, 0, 0, 0);
            rs = __builtin_amdgcn_mfma_f32_16x16x32_bf16(pa0, LDB(1, 0, cc), rs, 0, 0, 0);
            rs = __builtin_amdgcn_mfma_f32_16x16x32_bf16(pa1, LDB(1, 1, cc), rs, 0, 0, 0);
            zs = __builtin_amdgcn_mfma_f32_16x16x32_bf16(ha0, LDB(0, 0, cc + 4), zs, 0, 0, 0);
            zs = __builtin_amdgcn_mfma_f32_16x16x32_bf16(ha1, LDB(0, 1, cc + 4), zs, 0, 0, 0);
            zs = __builtin_amdgcn_mfma_f32_16x16x32_bf16(pa0, LDB(1, 0, cc + 4), zs, 0, 0, 0);
            zs = __builtin_amdgcn_mfma_f32_16x16x32_bf16(pa1, LDB(1, 1, cc + 4), zs, 0, 0, 0);
            gin = __builtin_amdgcn_mfma_f32_16x16x32_bf16(ha0, LDB(0, 0, cc + 8), gin, 0, 0, 0);
            gin = __builtin_amdgcn_mfma_f32_16x16x32_bf16(ha1, LDB(0, 1, cc + 8), gin, 0, 0, 0);
            ghn = __builtin_amdgcn_mfma_f32_16x16x32_bf16(pa0, LDB(1, 0, cc + 8), ghn, 0, 0, 0);
            ghn = __builtin_amdgcn_mfma_f32_16x16x32_bf16(pa1, LDB(1, 1, cc + 8), ghn, 0, 0, 0);
#undef LDB
#pragma unroll
            for (int rg = 0; rg < 4; ++rg) {
                int row = row0 + quad * 4 + rg;
                float pv = h_prev[(size_t)row * 64 + cc * 16 + l16];
                float rr = fast_sigmoid(rs[rg]);
                float zz = fast_sigmoid(zs[rg]);
                float nn = fast_tanh(gin[rg] + rr * ghn[rg]);
                float hn = (1.f - zz) * nn + zz * pv;
                out_h[(size_t)row * 64 + cc * 16 + l16] = hn;
                p[rg][0] += hn * wv[cc][0];
                p[rg][1] += hn * wv[cc][1];
                p[rg][2] += hn * wv[cc][2];
            }
        }
#pragma unroll
        for (int rg = 0; rg < 4; ++rg) {
#pragma unroll
            for (int m = 1; m < 16; m <<= 1) {
                p[rg][0] += __shfl_xor(p[rg][0], m);
                p[rg][1] += __shfl_xor(p[rg][1], m);
                p[rg][2] += __shfl_xor(p[rg][2], m);
            }
        }
        if (l16 == 0) {
#pragma unroll
            for (int rg = 0; rg < 4; ++rg) {
                int row = row0 + quad * 4 + rg;
                out_o[(size_t)row * 3 + 0] = p[rg][0] + bro0;
                out_o[(size_t)row * 3 + 1] = p[rg][1] + bro1;
                out_o[(size_t)row * 3 + 2] = p[rg][2] + bro2;
            }
        }
    }
}

extern "C" void kernel_launch(void* const* d_in, const int* in_sizes, int n_in,
                              void* d_out, int out_size, void* d_ws, size_t ws_size,
                              hipStream_t stream) {
    const float* x        = (const float*)d_in[0];
    const float* h_prev   = (const float*)d_in[1];
    const int* node_idx   = (const int*)d_in[2];
    const int* hedge_idx  = (const int*)d_in[3];
    const int* edge_attr  = (const int*)d_in[4];
    const float* W_conv   = (const float*)d_in[5];
    const float* b_conv   = (const float*)d_in[6];
    const float* W_mix    = (const float*)d_in[7];
    const float* b_mix    = (const float*)d_in[8];
    const float* W_ih     = (const float*)d_in[9];
    const float* W_hh     = (const float*)d_in[10];
    const float* b_ih     = (const float*)d_in[11];
    const float* b_hh     = (const float*)d_in[12];
    const float* W_ro     = (const float*)d_in[13];
    const float* b_ro     = (const float*)d_in[14];

    char* p = (char*)d_ws;
    auto alloc = [&](size_t bytes) {
        char* r = p;
        p += (bytes + 63) & ~(size_t)63;
        return r;
    };
    // Region A (25.6MB): bucket-sort scratch {pairs 12.8MB, rk12 3.2MB,
    // bcnt 0.55MB, bsum 4KB} — all dead after k_bfinal — overlaid by agg16
    // (first written in k_no2).
    char* regA     = alloc((size_t)2 * N_NODES * 64 * 2);   // 25.6 MB
    int2* pairs    = (int2*)regA;
    uint* rk12     = (uint*)(pairs + 2 * N_EDGES);
    int* bcnt      = (int*)(rk12 + N_EDGES);
    int* bsum      = bcnt + TOTB + 1;
    bf16* agg16    = (bf16*)regA;
    int* off       = (int*)alloc((size_t)(MSEG + 1) * 4);   // live CSR ptrs
    int* sortedAll = (int*)alloc((size_t)2 * N_EDGES * 4);
    bf16* xb       = (bf16*)alloc((size_t)N_NODES * 64 * 2);
    bf16* ef16     = (bf16*)alloc((size_t)HSEG * 64 * 2);
    bf16* gru_pk   = (bf16*)alloc((size_t)GRU_PK * 2);
    bf16* mixf_pk  = (bf16*)alloc((size_t)MIX_PK * 2);
    float* bfused  = (float*)alloc(64 * 4);

    float* out_h = (float*)d_out;
    float* out_o = out_h + (size_t)N_NODES * 64;

    k_front<<<NBLK_A + CAST_BLOCKS + PACK_BLOCKS, 256, 0, stream>>>(
        node_idx, hedge_idx, edge_attr, rk12, bcnt, x, xb,
        W_conv, W_mix, b_conv, b_mix, W_ih, W_hh, gru_pk, mixf_pk, bfused);
    k_scan1<<<SCANB, 256, 0, stream>>>(bcnt, bcnt, bsum);   // in-place
    k_scan2<<<1, 1024, 0, stream>>>(bsum);
    k_scan3<<<SCANB, 256, 0, stream>>>(bcnt, bsum);
    k_bscatter<<<NBLK_A, 256, 0, stream>>>(node_idx, hedge_idx, edge_attr,
                                           rk12, bcnt, pairs);
    k_bfinal<<<NBUCK, 256, 0, stream>>>(bcnt, pairs, off, sortedAll);
    k_ef2<<<HSEG / 16, 256, 0, stream>>>(off, sortedAll, xb, ef16);
    k_no2<<<NSEG / 16, 256, 0, stream>>>(off, sortedAll, ef16, agg16);
    k_mixgru<<<512, 512, 0, stream>>>(gru_pk, mixf_pk, bfused, agg16, h_prev,
                                      b_ih, b_hh, W_ro, b_ro, out_h, out_o);
}